// Round 1
// baseline (526.721 us; speedup 1.0000x reference)
//
#include <hip/hip_runtime.h>
#include <math.h>

// Problem constants (fixed by setup_inputs)
#define NB 32      // batch
#define NC 256     // channels
#define NS 1024    // spatial (32*32)
#define NG 32      // groups
#define EPSV 1e-5f
#define RS2 0.70710678118654752f  // 1/sqrt(2)
#define SC2 0.0625f               // C^-0.5 = 1/16

// ---------------- K1: 4x4 maxpool + SiLU -> qp[B][2][S] ----------------
__global__ void k_pool_silu(const float* __restrict__ cond, float* __restrict__ qp) {
    int idx = blockIdx.x * 256 + threadIdx.x;        // 65536 outputs
    int ow = idx & 31, oh = (idx >> 5) & 31;
    int bd = idx >> 10;                              // b*2+d
    const float* src = cond + (((size_t)bd * 128 + oh * 4) * 128 + ow * 4);
    float m = -1e30f;
#pragma unroll
    for (int r = 0; r < 4; ++r) {
        float4 v4 = *reinterpret_cast<const float4*>(src + (size_t)r * 128);
        m = fmaxf(m, fmaxf(fmaxf(v4.x, v4.y), fmaxf(v4.z, v4.w)));
    }
    qp[idx] = m / (1.f + __expf(-m));
}

// ---------------- K2: GroupNorm stats per (b,g) ----------------
__global__ void k_gn_stats(const float* __restrict__ x, float* __restrict__ mean,
                           float* __restrict__ rstd) {
    int bg = blockIdx.x;                 // 1024
    int t = threadIdx.x;                 // 256
    const float4* p = reinterpret_cast<const float4*>(x + (size_t)bg * 8192);
    float s = 0.f, ss = 0.f;
#pragma unroll
    for (int r = 0; r < 8; ++r) {
        float4 v4 = p[r * 256 + t];
        s  += v4.x + v4.y + v4.z + v4.w;
        ss += v4.x * v4.x + v4.y * v4.y + v4.z * v4.z + v4.w * v4.w;
    }
    for (int o = 32; o > 0; o >>= 1) { s += __shfl_xor(s, o); ss += __shfl_xor(ss, o); }
    __shared__ float ls[4], lss[4];
    int w = t >> 6;
    if ((t & 63) == 0) { ls[w] = s; lss[w] = ss; }
    __syncthreads();
    if (t == 0) {
        s = ls[0] + ls[1] + ls[2] + ls[3];
        ss = lss[0] + lss[1] + lss[2] + lss[3];
        float mn = s * (1.f / 8192.f);
        float var = ss * (1.f / 8192.f) - mn * mn;
        mean[bg] = mn;
        rstd[bg] = rsqrtf(var + EPSV);
    }
}

// ---------------- K3: GN apply + transpose -> h2n[B][S][C] ----------------
__global__ void k_gn_apply(const float* __restrict__ x, const float* __restrict__ mean,
                           const float* __restrict__ rstd, const float* __restrict__ gw,
                           const float* __restrict__ gb, float* __restrict__ h2n) {
    int bid = blockIdx.x;                      // 8192 = 32 * 32 * 8
    int b = bid >> 8, s0 = ((bid >> 3) & 31) << 5, c0 = (bid & 7) << 5;
    int tx = threadIdx.x, ty = threadIdx.y;    // (32,8)
    __shared__ float tile[32][33];
#pragma unroll
    for (int i = 0; i < 4; ++i) {
        int c = c0 + ty + 8 * i;
        float val = x[((size_t)(b * NC + c)) * NS + s0 + tx];
        int bg = b * NG + (c >> 3);
        val = (val - mean[bg]) * rstd[bg] * gw[c] + gb[c];
        tile[ty + 8 * i][tx] = val;            // [c_local][s_local]
    }
    __syncthreads();
#pragma unroll
    for (int i = 0; i < 4; ++i) {
        int s = s0 + ty + 8 * i;
        h2n[((size_t)(b * NS + s)) * NC + c0 + tx] = tile[tx][ty + 8 * i];
    }
}

// ------------- K4: fold k-half of fp1 through fp2 -> w0,w1,wb,z -------------
__global__ void k_prew(const float* __restrict__ fp1w, const float* __restrict__ fp1b,
                       const float* __restrict__ fp2w, const float* __restrict__ fp2b,
                       float* __restrict__ w0, float* __restrict__ w1,
                       float* __restrict__ wb, float* __restrict__ zs) {
    int c = threadIdx.x;   // 256
    float a0 = 0.f, a1 = 0.f, ab = 0.f;
    for (int kk = 0; kk < 256; ++kk) {
        float f = fp1w[(size_t)kk * 256 + c];
        a0 += f * fp2w[kk * 2];
        a1 += f * fp2w[kk * 2 + 1];
        ab += f * fp2b[kk];
    }
    w0[c] = a0; w1[c] = a1; wb[c] = ab;
    if (c == 0) {
        float z0 = 0.f, z1 = 0.f, zb = 0.f;
        for (int kk = 0; kk < 256; ++kk) {
            float fb = fp1b[kk];
            z0 += fb * fp2w[kk * 2];
            z1 += fb * fp2w[kk * 2 + 1];
            zb += fb * fp2b[kk];
        }
        zs[0] = z0; zs[1] = z1; zs[2] = zb; zs[3] = 0.f;
    }
}

// ------------- K5: V = h2n @ fp1_w[v-half]^T + fp1_b[v-half] -------------
// C[m][n] = sum_k A[m][k]*W[n][k] + bias[n].  A:[32768][256], W:[256][256]
__global__ __launch_bounds__(256) void k_gemm_v(const float* __restrict__ A,
                                                const float* __restrict__ W,
                                                const float* __restrict__ bias,
                                                float* __restrict__ Cout) {
    int bid = blockIdx.x;              // (M/64)*(N/64) = 512*4
    int n0 = (bid & 3) << 6;
    int m0 = (bid >> 2) << 6;
    int t = threadIdx.x;
    __shared__ float As[16][68];
    __shared__ float Bs[16][68];
    int lm = t >> 2, lk4 = (t & 3) << 2;
    int tm = t & 15, tn = t >> 4;
    float acc[4][4] = {};
    for (int k0 = 0; k0 < 256; k0 += 16) {
        float4 a4 = *reinterpret_cast<const float4*>(A + (size_t)(m0 + lm) * 256 + k0 + lk4);
        float4 b4 = *reinterpret_cast<const float4*>(W + (size_t)(n0 + lm) * 256 + k0 + lk4);
        __syncthreads();
        As[lk4 + 0][lm] = a4.x; As[lk4 + 1][lm] = a4.y; As[lk4 + 2][lm] = a4.z; As[lk4 + 3][lm] = a4.w;
        Bs[lk4 + 0][lm] = b4.x; Bs[lk4 + 1][lm] = b4.y; Bs[lk4 + 2][lm] = b4.z; Bs[lk4 + 3][lm] = b4.w;
        __syncthreads();
#pragma unroll
        for (int kk = 0; kk < 16; ++kk) {
            float4 av = *reinterpret_cast<const float4*>(&As[kk][tm * 4]);
            float4 bv = *reinterpret_cast<const float4*>(&Bs[kk][tn * 4]);
            float ar[4] = {av.x, av.y, av.z, av.w};
            float br[4] = {bv.x, bv.y, bv.z, bv.w};
#pragma unroll
            for (int i = 0; i < 4; ++i)
#pragma unroll
                for (int j = 0; j < 4; ++j) acc[i][j] += ar[i] * br[j];
        }
    }
    float bj[4];
#pragma unroll
    for (int j = 0; j < 4; ++j) bj[j] = bias[n0 + tn * 4 + j];
#pragma unroll
    for (int i = 0; i < 4; ++i) {
        int m = m0 + tm * 4 + i;
        float4 o4 = make_float4(acc[i][0] + bj[0], acc[i][1] + bj[1],
                                acc[i][2] + bj[2], acc[i][3] + bj[3]);
        *reinterpret_cast<float4*>(Cout + (size_t)m * 256 + n0 + tn * 4) = o4;
    }
}

// ------------- K6: kp0/kp1/kb per row from h2n -------------
__global__ void k_kp(const float* __restrict__ h2n, const float* __restrict__ w0,
                     const float* __restrict__ w1, const float* __restrict__ wb,
                     const float* __restrict__ zs, float4* __restrict__ kp4) {
    int row = blockIdx.x * 4 + (threadIdx.x >> 6);   // 32768 rows
    int lane = threadIdx.x & 63;
    const float* h = h2n + (size_t)row * 256;
    float a0 = 0.f, a1 = 0.f, ab = 0.f;
#pragma unroll
    for (int q = 0; q < 4; ++q) {
        int c = lane + 64 * q;
        float hv = h[c];
        a0 += hv * w0[c]; a1 += hv * w1[c]; ab += hv * wb[c];
    }
    for (int o = 32; o > 0; o >>= 1) {
        a0 += __shfl_xor(a0, o); a1 += __shfl_xor(a1, o); ab += __shfl_xor(ab, o);
    }
    if (lane == 0) kp4[row] = make_float4(a0 + zs[0], a1 + zs[1], ab + zs[2], 0.f);
}

// ------------- K7: per-row softmax max & denominator -------------
__global__ void k_rowstats(const float4* __restrict__ kp4, const float* __restrict__ qp,
                           float2* __restrict__ mz) {
    int row = blockIdx.x * 4 + (threadIdx.x >> 6);   // 32768
    int lane = threadIdx.x & 63;
    int b = row >> 10, i = row & 1023;
    float qa = qp[(size_t)(b * 2) * NS + i];
    float qb = qp[(size_t)(b * 2 + 1) * NS + i];
    const float4* kp = kp4 + (size_t)b * NS;
    float l[16];
    float m = -1e30f;
#pragma unroll
    for (int tq = 0; tq < 16; ++tq) {
        float4 k4 = kp[lane + 64 * tq];
        float lv = SC2 * (qa * k4.x + qb * k4.y + k4.z);
        l[tq] = lv;
        m = fmaxf(m, lv);
    }
    for (int o = 32; o > 0; o >>= 1) m = fmaxf(m, __shfl_xor(m, o));
    float z = 0.f;
#pragma unroll
    for (int tq = 0; tq < 16; ++tq) z += __expf(l[tq] - m);
    for (int o = 32; o > 0; o >>= 1) z += __shfl_xor(z, o);
    if (lane == 0) mz[row] = make_float2(m, z);
}

// ------------- K8: PV — out_attn[b][i][c] = softmax(l) @ v -------------
// block: 64 i-rows x 256 c-cols; 256 threads: g = t>>6 owns rows g*16..g*16+15,
// col4 = (t&63)*4 owns 4 contiguous channels.
__global__ __launch_bounds__(256) void k_pv(const float* __restrict__ v,
                                            const float4* __restrict__ kp4,
                                            const float* __restrict__ qp,
                                            const float2* __restrict__ mz,
                                            float* __restrict__ oat) {
    int bid = blockIdx.x;              // b*16 + it
    int b = bid >> 4, i0 = (bid & 15) << 6;
    int t = threadIdx.x;
    int g = t >> 6, lane = t & 63;
    int col4 = lane * 4;
    __shared__ float es[64 * 64];
    __shared__ float ra[64], rb[64], rm[64], rz[64];
    if (t < 64) {
        int row = b * NS + i0 + t;
        ra[t] = qp[(size_t)(b * 2) * NS + i0 + t];
        rb[t] = qp[(size_t)(b * 2 + 1) * NS + i0 + t];
        float2 z2 = mz[row];
        rm[t] = z2.x;
        rz[t] = 1.f / z2.y;
    }
    float acc[16][4] = {};
    __syncthreads();
    float sa = ra[lane], sb = rb[lane], sm = rm[lane];
    const float* vb = v + (size_t)b * NS * NC;
    const float4* kp = kp4 + (size_t)b * NS;
    for (int jc = 0; jc < 16; ++jc) {
        int j0 = jc << 6;
#pragma unroll
        for (int r = 0; r < 16; ++r) {
            int jj = g + 4 * r;
            float4 k4 = kp[j0 + jj];
            float e = __expf(SC2 * (sa * k4.x + sb * k4.y + k4.z) - sm);
            es[jj * 64 + lane] = e;
        }
        __syncthreads();
#pragma unroll 2
        for (int jj = 0; jj < 64; ++jj) {
            const float* ep = &es[jj * 64 + g * 16];
            float4 vv = *reinterpret_cast<const float4*>(vb + (size_t)(j0 + jj) * NC + col4);
#pragma unroll
            for (int eq = 0; eq < 4; ++eq) {
                float4 ev = *reinterpret_cast<const float4*>(ep + 4 * eq);
                int i4 = eq * 4;
                acc[i4 + 0][0] += ev.x * vv.x; acc[i4 + 0][1] += ev.x * vv.y;
                acc[i4 + 0][2] += ev.x * vv.z; acc[i4 + 0][3] += ev.x * vv.w;
                acc[i4 + 1][0] += ev.y * vv.x; acc[i4 + 1][1] += ev.y * vv.y;
                acc[i4 + 1][2] += ev.y * vv.z; acc[i4 + 1][3] += ev.y * vv.w;
                acc[i4 + 2][0] += ev.z * vv.x; acc[i4 + 2][1] += ev.z * vv.y;
                acc[i4 + 2][2] += ev.z * vv.z; acc[i4 + 2][3] += ev.z * vv.w;
                acc[i4 + 3][0] += ev.w * vv.x; acc[i4 + 3][1] += ev.w * vv.y;
                acc[i4 + 3][2] += ev.w * vv.z; acc[i4 + 3][3] += ev.w * vv.w;
            }
        }
        __syncthreads();
    }
#pragma unroll
    for (int ii = 0; ii < 16; ++ii) {
        int rl = g * 16 + ii;
        float zi = rz[rl];
        float4 o4 = make_float4(acc[ii][0] * zi, acc[ii][1] * zi,
                                acc[ii][2] * zi, acc[ii][3] * zi);
        *reinterpret_cast<float4*>(oat + ((size_t)(b * NS + i0 + rl)) * NC + col4) = o4;
    }
}

// ------------- K9: out = oat @ out_w^T + out_b; residual; /sqrt2; transpose -------------
__global__ __launch_bounds__(256) void k_gemm_out(const float* __restrict__ A,
                                                  const float* __restrict__ W,
                                                  const float* __restrict__ bias,
                                                  const float* __restrict__ x,
                                                  float* __restrict__ Cout) {
    int bid = blockIdx.x;
    int n0 = (bid & 3) << 6;
    int m0 = (bid >> 2) << 6;
    int t = threadIdx.x;
    __shared__ float As[16][68];
    __shared__ float Bs[16][68];
    int lm = t >> 2, lk4 = (t & 3) << 2;
    int tm = t & 15, tn = t >> 4;
    float acc[4][4] = {};
    for (int k0 = 0; k0 < 256; k0 += 16) {
        float4 a4 = *reinterpret_cast<const float4*>(A + (size_t)(m0 + lm) * 256 + k0 + lk4);
        float4 b4 = *reinterpret_cast<const float4*>(W + (size_t)(n0 + lm) * 256 + k0 + lk4);
        __syncthreads();
        As[lk4 + 0][lm] = a4.x; As[lk4 + 1][lm] = a4.y; As[lk4 + 2][lm] = a4.z; As[lk4 + 3][lm] = a4.w;
        Bs[lk4 + 0][lm] = b4.x; Bs[lk4 + 1][lm] = b4.y; Bs[lk4 + 2][lm] = b4.z; Bs[lk4 + 3][lm] = b4.w;
        __syncthreads();
#pragma unroll
        for (int kk = 0; kk < 16; ++kk) {
            float4 av = *reinterpret_cast<const float4*>(&As[kk][tm * 4]);
            float4 bv = *reinterpret_cast<const float4*>(&Bs[kk][tn * 4]);
            float ar[4] = {av.x, av.y, av.z, av.w};
            float br[4] = {bv.x, bv.y, bv.z, bv.w};
#pragma unroll
            for (int i = 0; i < 4; ++i)
#pragma unroll
                for (int j = 0; j < 4; ++j) acc[i][j] += ar[i] * br[j];
        }
    }
    float bj[4];
#pragma unroll
    for (int j = 0; j < 4; ++j) bj[j] = bias[n0 + tn * 4 + j];
#pragma unroll
    for (int i = 0; i < 4; ++i) {
        int m = m0 + tm * 4 + i;
        int b = m >> 10, s = m & 1023;
#pragma unroll
        for (int j = 0; j < 4; ++j) {
            int n = n0 + tn * 4 + j;
            size_t oi = ((size_t)(b * NC + n)) * NS + s;
            Cout[oi] = (acc[i][j] + bj[j] + x[oi]) * RS2;
        }
    }
}

extern "C" void kernel_launch(void* const* d_in, const int* in_sizes, int n_in,
                              void* d_out, int out_size, void* d_ws, size_t ws_size,
                              hipStream_t stream) {
    const float* x     = (const float*)d_in[0];
    const float* cond  = (const float*)d_in[1];
    const float* gn_w  = (const float*)d_in[2];
    const float* gn_b  = (const float*)d_in[3];
    const float* fp1_w = (const float*)d_in[4];
    const float* fp1_b = (const float*)d_in[5];
    const float* fp2_w = (const float*)d_in[6];
    const float* fp2_b = (const float*)d_in[7];
    const float* out_w = (const float*)d_in[8];
    const float* out_b = (const float*)d_in[9];

    float* ws   = (float*)d_ws;
    float* qp   = ws;                      // 65536
    float* mean = ws + 65536;              // 1024
    float* rstd = ws + 66560;              // 1024
    float* w0   = ws + 67584;              // 256
    float* w1   = ws + 67840;              // 256
    float* wb   = ws + 68096;              // 256
    float* zs   = ws + 68352;              // 4 (pad to 256)
    float* h2n  = ws + 68608;              // 8388608  (reused as oat after last read)
    float* vbuf = h2n + 8388608;           // 8388608
    float* kp4  = vbuf + 8388608;          // 131072  (float4[32768])
    float* mzb  = kp4 + 131072;            // 65536   (float2[32768])
    float* oat  = h2n;                     // alias: h2n dead after k_kp

    k_pool_silu<<<256, 256, 0, stream>>>(cond, qp);
    k_gn_stats<<<1024, 256, 0, stream>>>(x, mean, rstd);
    k_gn_apply<<<8192, dim3(32, 8), 0, stream>>>(x, mean, rstd, gn_w, gn_b, h2n);
    k_prew<<<1, 256, 0, stream>>>(fp1_w, fp1_b, fp2_w, fp2_b, w0, w1, wb, zs);
    k_gemm_v<<<2048, 256, 0, stream>>>(h2n, fp1_w + 256 * 256, fp1_b + 256, vbuf);
    k_kp<<<8192, 256, 0, stream>>>(h2n, w0, w1, wb, zs, (float4*)kp4);
    k_rowstats<<<8192, 256, 0, stream>>>((const float4*)kp4, qp, (float2*)mzb);
    k_pv<<<512, 256, 0, stream>>>(vbuf, (const float4*)kp4, qp, (const float2*)mzb, oat);
    k_gemm_out<<<2048, 256, 0, stream>>>(oat, out_w, out_b, x, (float*)d_out);
}

// Round 2
// 261.387 us; speedup vs baseline: 2.0151x; 2.0151x over previous
//
#include <hip/hip_runtime.h>
#include <math.h>

// Problem constants (fixed by setup_inputs)
#define NB 32      // batch
#define NC 256     // channels
#define NS 1024    // spatial (32*32)
#define NG 32      // groups
#define EPSV 1e-5f
#define RS2 0.70710678118654752f  // 1/sqrt(2)
#define SC2 0.0625f               // C^-0.5 = 1/16

typedef __attribute__((ext_vector_type(8))) short s16x8;
typedef __attribute__((ext_vector_type(4))) float f32x4;

__device__ __forceinline__ unsigned short f2bf(float f) {
    unsigned u = __float_as_uint(f);
    return (unsigned short)((u + 0x7fffu + ((u >> 16) & 1u)) >> 16);
}

// ---------------- K1: 4x4 maxpool + SiLU -> qp[B][2][S] ----------------
__global__ void k_pool_silu(const float* __restrict__ cond, float* __restrict__ qp) {
    int idx = blockIdx.x * 256 + threadIdx.x;        // 65536 outputs
    int ow = idx & 31, oh = (idx >> 5) & 31;
    int bd = idx >> 10;                              // b*2+d
    const float* src = cond + (((size_t)bd * 128 + oh * 4) * 128 + ow * 4);
    float m = -1e30f;
#pragma unroll
    for (int r = 0; r < 4; ++r) {
        float4 v4 = *reinterpret_cast<const float4*>(src + (size_t)r * 128);
        m = fmaxf(m, fmaxf(fmaxf(v4.x, v4.y), fmaxf(v4.z, v4.w)));
    }
    qp[idx] = m / (1.f + __expf(-m));
}

// ---------------- K2: GroupNorm stats per (b,g) ----------------
__global__ void k_gn_stats(const float* __restrict__ x, float* __restrict__ mean,
                           float* __restrict__ rstd) {
    int bg = blockIdx.x;                 // 1024
    int t = threadIdx.x;                 // 256
    const float4* p = reinterpret_cast<const float4*>(x + (size_t)bg * 8192);
    float s = 0.f, ss = 0.f;
#pragma unroll
    for (int r = 0; r < 8; ++r) {
        float4 v4 = p[r * 256 + t];
        s  += v4.x + v4.y + v4.z + v4.w;
        ss += v4.x * v4.x + v4.y * v4.y + v4.z * v4.z + v4.w * v4.w;
    }
    for (int o = 32; o > 0; o >>= 1) { s += __shfl_xor(s, o); ss += __shfl_xor(ss, o); }
    __shared__ float ls[4], lss[4];
    int w = t >> 6;
    if ((t & 63) == 0) { ls[w] = s; lss[w] = ss; }
    __syncthreads();
    if (t == 0) {
        s = ls[0] + ls[1] + ls[2] + ls[3];
        ss = lss[0] + lss[1] + lss[2] + lss[3];
        float mn = s * (1.f / 8192.f);
        float var = ss * (1.f / 8192.f) - mn * mn;
        mean[bg] = mn;
        rstd[bg] = rsqrtf(var + EPSV);
    }
}

// ---------------- K3: GN apply + transpose -> h2n[B][S][C] ----------------
__global__ void k_gn_apply(const float* __restrict__ x, const float* __restrict__ mean,
                           const float* __restrict__ rstd, const float* __restrict__ gw,
                           const float* __restrict__ gb, float* __restrict__ h2n) {
    int bid = blockIdx.x;                      // 8192 = 32 * 32 * 8
    int b = bid >> 8, s0 = ((bid >> 3) & 31) << 5, c0 = (bid & 7) << 5;
    int tx = threadIdx.x, ty = threadIdx.y;    // (32,8)
    __shared__ float tile[32][33];
#pragma unroll
    for (int i = 0; i < 4; ++i) {
        int c = c0 + ty + 8 * i;
        float val = x[((size_t)(b * NC + c)) * NS + s0 + tx];
        int bg = b * NG + (c >> 3);
        val = (val - mean[bg]) * rstd[bg] * gw[c] + gb[c];
        tile[ty + 8 * i][tx] = val;            // [c_local][s_local]
    }
    __syncthreads();
#pragma unroll
    for (int i = 0; i < 4; ++i) {
        int s = s0 + ty + 8 * i;
        h2n[((size_t)(b * NS + s)) * NC + c0 + tx] = tile[tx][ty + 8 * i];
    }
}

// ------------- K4: fold k-half of fp1 through fp2 -> w0,w1,wb,z -------------
__global__ void k_prew(const float* __restrict__ fp1w, const float* __restrict__ fp1b,
                       const float* __restrict__ fp2w, const float* __restrict__ fp2b,
                       float* __restrict__ w0, float* __restrict__ w1,
                       float* __restrict__ wb, float* __restrict__ zs) {
    int c = threadIdx.x;   // 256
    float a0 = 0.f, a1 = 0.f, ab = 0.f;
    for (int kk = 0; kk < 256; ++kk) {
        float f = fp1w[(size_t)kk * 256 + c];
        a0 += f * fp2w[kk * 2];
        a1 += f * fp2w[kk * 2 + 1];
        ab += f * fp2b[kk];
    }
    w0[c] = a0; w1[c] = a1; wb[c] = ab;
    if (c == 0) {
        float z0 = 0.f, z1 = 0.f, zb = 0.f;
        for (int kk = 0; kk < 256; ++kk) {
            float fb = fp1b[kk];
            z0 += fb * fp2w[kk * 2];
            z1 += fb * fp2w[kk * 2 + 1];
            zb += fb * fp2b[kk];
        }
        zs[0] = z0; zs[1] = z1; zs[2] = zb; zs[3] = 0.f;
    }
}

// ------------- K5: V = h2n @ fp1_w[v-half]^T + b, written as bf16 in the
//                swizzled fragment layout vtg[b][kc][c][granule^swz][jj] -------------
__global__ __launch_bounds__(256) void k_gemm_v(const float* __restrict__ A,
                                                const float* __restrict__ W,
                                                const float* __restrict__ bias,
                                                unsigned short* __restrict__ vtg) {
    int bid = blockIdx.x;              // (M/64)*(N/64) = 512*4
    int n0 = (bid & 3) << 6;
    int m0 = (bid >> 2) << 6;
    int t = threadIdx.x;
    __shared__ float As[16][68];
    __shared__ float Bs[16][68];
    int lm = t >> 2, lk4 = (t & 3) << 2;
    int tm = t & 15, tn = t >> 4;
    float acc[4][4] = {};
    for (int k0 = 0; k0 < 256; k0 += 16) {
        float4 a4 = *reinterpret_cast<const float4*>(A + (size_t)(m0 + lm) * 256 + k0 + lk4);
        float4 b4 = *reinterpret_cast<const float4*>(W + (size_t)(n0 + lm) * 256 + k0 + lk4);
        __syncthreads();
        As[lk4 + 0][lm] = a4.x; As[lk4 + 1][lm] = a4.y; As[lk4 + 2][lm] = a4.z; As[lk4 + 3][lm] = a4.w;
        Bs[lk4 + 0][lm] = b4.x; Bs[lk4 + 1][lm] = b4.y; Bs[lk4 + 2][lm] = b4.z; Bs[lk4 + 3][lm] = b4.w;
        __syncthreads();
#pragma unroll
        for (int kk = 0; kk < 16; ++kk) {
            float4 av = *reinterpret_cast<const float4*>(&As[kk][tm * 4]);
            float4 bv = *reinterpret_cast<const float4*>(&Bs[kk][tn * 4]);
            float ar[4] = {av.x, av.y, av.z, av.w};
            float br[4] = {bv.x, bv.y, bv.z, bv.w};
#pragma unroll
            for (int i = 0; i < 4; ++i)
#pragma unroll
                for (int j = 0; j < 4; ++j) acc[i][j] += ar[i] * br[j];
        }
    }
    float bj[4];
#pragma unroll
    for (int j = 0; j < 4; ++j) bj[j] = bias[n0 + tn * 4 + j];
#pragma unroll
    for (int i = 0; i < 4; ++i) {
        int m = m0 + tm * 4 + i;
        int bb = m >> 10, s = m & 1023;
        int kc = s >> 5, jl = s & 31;
        size_t cb = ((size_t)(bb * 32 + kc)) << 13;   // chunk base, ushort units
#pragma unroll
        for (int j = 0; j < 4; ++j) {
            int n = n0 + tn * 4 + j;
            int g = (jl >> 3) ^ ((n >> 1) & 3);
            vtg[cb + n * 32 + (g << 3) + (jl & 7)] = f2bf(acc[i][j] + bj[j]);
        }
    }
}

// ------------- K6: kp0/kp1/kb per row from h2n (pre-scaled by SC2) -------------
__global__ void k_kp(const float* __restrict__ h2n, const float* __restrict__ w0,
                     const float* __restrict__ w1, const float* __restrict__ wb,
                     const float* __restrict__ zs, float4* __restrict__ kp4) {
    int row = blockIdx.x * 4 + (threadIdx.x >> 6);   // 32768 rows
    int lane = threadIdx.x & 63;
    const float* h = h2n + (size_t)row * 256;
    float a0 = 0.f, a1 = 0.f, ab = 0.f;
#pragma unroll
    for (int q = 0; q < 4; ++q) {
        int c = lane + 64 * q;
        float hv = h[c];
        a0 += hv * w0[c]; a1 += hv * w1[c]; ab += hv * wb[c];
    }
    for (int o = 32; o > 0; o >>= 1) {
        a0 += __shfl_xor(a0, o); a1 += __shfl_xor(a1, o); ab += __shfl_xor(ab, o);
    }
    if (lane == 0)
        kp4[row] = make_float4((a0 + zs[0]) * SC2, (a1 + zs[1]) * SC2, (ab + zs[2]) * SC2, 0.f);
}

// ------------- K7: per-row softmax max & denominator (kp pre-scaled) -------------
__global__ void k_rowstats(const float4* __restrict__ kp4, const float* __restrict__ qp,
                           float2* __restrict__ mz) {
    int row = blockIdx.x * 4 + (threadIdx.x >> 6);   // 32768
    int lane = threadIdx.x & 63;
    int b = row >> 10, i = row & 1023;
    float qa = qp[(size_t)(b * 2) * NS + i];
    float qb = qp[(size_t)(b * 2 + 1) * NS + i];
    const float4* kp = kp4 + (size_t)b * NS;
    float l[16];
    float m = -1e30f;
#pragma unroll
    for (int tq = 0; tq < 16; ++tq) {
        float4 k4 = kp[lane + 64 * tq];
        float lv = qa * k4.x + qb * k4.y + k4.z;
        l[tq] = lv;
        m = fmaxf(m, lv);
    }
    for (int o = 32; o > 0; o >>= 1) m = fmaxf(m, __shfl_xor(m, o));
    float z = 0.f;
#pragma unroll
    for (int tq = 0; tq < 16; ++tq) z += __expf(l[tq] - m);
    for (int o = 32; o > 0; o >>= 1) z += __shfl_xor(z, o);
    if (lane == 0) mz[row] = make_float2(m, z);
}

// ------------- K8: PV via MFMA bf16 -------------
// block: 64 i-rows x 256 c-cols, 4 waves; wave w owns c in [w*64, w*64+64).
// Per K-chunk (32 j): P(64x32) produced once into LDS (bf16, granule-swizzled),
// V chunk (256c x 32j bf16) staged linearly from the pre-swizzled global layout.
__global__ __launch_bounds__(256) void k_pv_mfma(const unsigned short* __restrict__ vtg,
                                                 const float4* __restrict__ kp4,
                                                 const float* __restrict__ qp,
                                                 const float2* __restrict__ mz,
                                                 float* __restrict__ oat) {
    int bid = blockIdx.x;              // b*16 + it
    int b = bid >> 4, i0 = (bid & 15) << 6;
    int t = threadIdx.x;
    int w = t >> 6, lane = t & 63;
    int lo16 = lane & 15, q = lane >> 4;

    __shared__ uint4 vt4[1024];        // 16 KB: V chunk [c:256][64B]
    __shared__ uint4 pt4[256];         //  4 KB: P tile  [i:64][64B]
    __shared__ float rqa[64], rqb[64], rm[64], rz[64];
    unsigned short* vtu = (unsigned short*)vt4;
    unsigned short* ptu = (unsigned short*)pt4;

    if (t < 64) {
        int row = b * NS + i0 + t;
        rqa[t] = qp[(size_t)(b * 2) * NS + i0 + t];
        rqb[t] = qp[(size_t)(b * 2 + 1) * NS + i0 + t];
        float2 z2 = mz[row];
        rm[t] = z2.x;
        rz[t] = 1.f / z2.y;
    }
    __syncthreads();

    f32x4 acc[4][4];
    const f32x4 zero4 = {0.f, 0.f, 0.f, 0.f};
#pragma unroll
    for (int f = 0; f < 4; ++f)
#pragma unroll
        for (int ct = 0; ct < 4; ++ct) acc[f][ct] = zero4;

    int pj = t & 31, pig = t >> 5;     // producer: column j, row-group of 8
    const float4* kpb = kp4 + ((size_t)b << 10);
    const uint4* gv = (const uint4*)vtg;

    for (int kc = 0; kc < 32; ++kc) {
        // issue V-chunk loads early (16 KB linear copy)
        const uint4* gsrc = gv + (((size_t)(b * 32 + kc)) << 10);
        uint4 dA = gsrc[t], dB = gsrc[t + 256], dC = gsrc[t + 512], dD = gsrc[t + 768];
        // produce P values for this chunk (rank-3 logits -> exp)
        float4 kk = kpb[(kc << 5) + pj];
        unsigned short pe[8];
#pragma unroll
        for (int r = 0; r < 8; ++r) {
            int i = pig * 8 + r;
            float l = fmaf(rqa[i], kk.x, fmaf(rqb[i], kk.y, kk.z)) - rm[i];
            pe[r] = f2bf(__expf(l));
        }
        __syncthreads();               // previous iteration's reads done
        vt4[t] = dA; vt4[t + 256] = dB; vt4[t + 512] = dC; vt4[t + 768] = dD;
#pragma unroll
        for (int r = 0; r < 8; ++r) {
            int i = pig * 8 + r;
            ptu[(i << 5) + (((pj >> 3) ^ ((i >> 1) & 3)) << 3) + (pj & 7)] = pe[r];
        }
        __syncthreads();               // tiles ready
        // compute: 4 a-frags + 4 b-frags -> 16 MFMA
        s16x8 af[4];
#pragma unroll
        for (int f = 0; f < 4; ++f) {
            int i = f * 16 + lo16;
            af[f] = *(const s16x8*)&ptu[(i << 5) + ((q ^ ((i >> 1) & 3)) << 3)];
        }
#pragma unroll
        for (int ct = 0; ct < 4; ++ct) {
            int c = w * 64 + ct * 16 + lo16;
            s16x8 bf = *(const s16x8*)&vtu[(c << 5) + ((q ^ ((c >> 1) & 3)) << 3)];
#pragma unroll
            for (int f = 0; f < 4; ++f)
                acc[f][ct] = __builtin_amdgcn_mfma_f32_16x16x32_bf16(af[f], bf, acc[f][ct], 0, 0, 0);
        }
    }

    // epilogue: scale by 1/z, store fp32 oat[b][i][c]
    float* obase = oat + ((size_t)(b * NS + i0)) * NC;
#pragma unroll
    for (int f = 0; f < 4; ++f) {
#pragma unroll
        for (int ct = 0; ct < 4; ++ct) {
            int c = w * 64 + ct * 16 + lo16;
#pragma unroll
            for (int reg = 0; reg < 4; ++reg) {
                int il = f * 16 + q * 4 + reg;
                obase[(size_t)il * NC + c] = acc[f][ct][reg] * rz[il];
            }
        }
    }
}

// ------------- K9: out = oat @ out_w^T + out_b; residual; /sqrt2; transpose -------------
__global__ __launch_bounds__(256) void k_gemm_out(const float* __restrict__ A,
                                                  const float* __restrict__ W,
                                                  const float* __restrict__ bias,
                                                  const float* __restrict__ x,
                                                  float* __restrict__ Cout) {
    int bid = blockIdx.x;
    int n0 = (bid & 3) << 6;
    int m0 = (bid >> 2) << 6;
    int t = threadIdx.x;
    __shared__ float As[16][68];
    __shared__ float Bs[16][68];
    int lm = t >> 2, lk4 = (t & 3) << 2;
    int tm = t & 15, tn = t >> 4;
    float acc[4][4] = {};
    for (int k0 = 0; k0 < 256; k0 += 16) {
        float4 a4 = *reinterpret_cast<const float4*>(A + (size_t)(m0 + lm) * 256 + k0 + lk4);
        float4 b4 = *reinterpret_cast<const float4*>(W + (size_t)(n0 + lm) * 256 + k0 + lk4);
        __syncthreads();
        As[lk4 + 0][lm] = a4.x; As[lk4 + 1][lm] = a4.y; As[lk4 + 2][lm] = a4.z; As[lk4 + 3][lm] = a4.w;
        Bs[lk4 + 0][lm] = b4.x; Bs[lk4 + 1][lm] = b4.y; Bs[lk4 + 2][lm] = b4.z; Bs[lk4 + 3][lm] = b4.w;
        __syncthreads();
#pragma unroll
        for (int kk = 0; kk < 16; ++kk) {
            float4 av = *reinterpret_cast<const float4*>(&As[kk][tm * 4]);
            float4 bv = *reinterpret_cast<const float4*>(&Bs[kk][tn * 4]);
            float ar[4] = {av.x, av.y, av.z, av.w};
            float br[4] = {bv.x, bv.y, bv.z, bv.w};
#pragma unroll
            for (int i = 0; i < 4; ++i)
#pragma unroll
                for (int j = 0; j < 4; ++j) acc[i][j] += ar[i] * br[j];
        }
    }
    float bj[4];
#pragma unroll
    for (int j = 0; j < 4; ++j) bj[j] = bias[n0 + tn * 4 + j];
#pragma unroll
    for (int i = 0; i < 4; ++i) {
        int m = m0 + tm * 4 + i;
        int b = m >> 10, s = m & 1023;
#pragma unroll
        for (int j = 0; j < 4; ++j) {
            int n = n0 + tn * 4 + j;
            size_t oi = ((size_t)(b * NC + n)) * NS + s;
            Cout[oi] = (acc[i][j] + bj[j] + x[oi]) * RS2;
        }
    }
}

extern "C" void kernel_launch(void* const* d_in, const int* in_sizes, int n_in,
                              void* d_out, int out_size, void* d_ws, size_t ws_size,
                              hipStream_t stream) {
    const float* x     = (const float*)d_in[0];
    const float* cond  = (const float*)d_in[1];
    const float* gn_w  = (const float*)d_in[2];
    const float* gn_b  = (const float*)d_in[3];
    const float* fp1_w = (const float*)d_in[4];
    const float* fp1_b = (const float*)d_in[5];
    const float* fp2_w = (const float*)d_in[6];
    const float* fp2_b = (const float*)d_in[7];
    const float* out_w = (const float*)d_in[8];
    const float* out_b = (const float*)d_in[9];

    float* ws   = (float*)d_ws;
    float* qp   = ws;                      // 65536
    float* mean = ws + 65536;              // 1024
    float* rstd = ws + 66560;              // 1024
    float* w0   = ws + 67584;              // 256
    float* w1   = ws + 67840;              // 256
    float* wb   = ws + 68096;              // 256
    float* zs   = ws + 68352;              // 4 (pad to 256)
    float* h2n  = ws + 68608;              // 8388608 fp32 (reused as oat)
    float* kp4  = h2n + 8388608;           // 131072  (float4[32768])
    float* mzb  = kp4 + 131072;            // 65536   (float2[32768])
    unsigned short* vtg = (unsigned short*)(mzb + 65536);  // 8388608 ushorts = 16 MB
    float* oat  = h2n;                     // alias: h2n dead after k_kp

    k_pool_silu<<<256, 256, 0, stream>>>(cond, qp);
    k_gn_stats<<<1024, 256, 0, stream>>>(x, mean, rstd);
    k_gn_apply<<<8192, dim3(32, 8), 0, stream>>>(x, mean, rstd, gn_w, gn_b, h2n);
    k_prew<<<1, 256, 0, stream>>>(fp1_w, fp1_b, fp2_w, fp2_b, w0, w1, wb, zs);
    k_gemm_v<<<2048, 256, 0, stream>>>(h2n, fp1_w + 256 * 256, fp1_b + 256, vtg);
    k_kp<<<8192, 256, 0, stream>>>(h2n, w0, w1, wb, zs, (float4*)kp4);
    k_rowstats<<<8192, 256, 0, stream>>>((const float4*)kp4, qp, (float2*)mzb);
    k_pv_mfma<<<512, 256, 0, stream>>>(vtg, (const float4*)kp4, qp, (const float2*)mzb, oat);
    k_gemm_out<<<2048, 256, 0, stream>>>(oat, out_w, out_b, x, (float*)d_out);
}

// Round 3
// 144.833 us; speedup vs baseline: 3.6367x; 1.8047x over previous
//
#include <hip/hip_runtime.h>
#include <math.h>

// Problem constants (fixed by setup_inputs)
#define NB 32      // batch
#define NC 256     // channels
#define NS 1024    // spatial (32*32)
#define NG 32      // groups
#define EPSV 1e-5f
#define RS2 0.70710678118654752f  // 1/sqrt(2)
#define SC2 0.0625f               // C^-0.5 = 1/16

typedef __attribute__((ext_vector_type(8))) short s16x8;
typedef __attribute__((ext_vector_type(4))) float f32x4;

__device__ __forceinline__ unsigned short f2bf(float f) {
    unsigned u = __float_as_uint(f);
    return (unsigned short)((u + 0x7fffu + ((u >> 16) & 1u)) >> 16);
}
__device__ __forceinline__ float bf2f(unsigned u16) {
    return __uint_as_float(u16 << 16);
}

// ---------------- K1: 4x4 maxpool + SiLU -> qp[B][2][S] ----------------
__global__ void k_pool_silu(const float* __restrict__ cond, float* __restrict__ qp) {
    int idx = blockIdx.x * 256 + threadIdx.x;        // 65536 outputs
    int ow = idx & 31, oh = (idx >> 5) & 31;
    int bd = idx >> 10;                              // b*2+d
    const float* src = cond + (((size_t)bd * 128 + oh * 4) * 128 + ow * 4);
    float m = -1e30f;
#pragma unroll
    for (int r = 0; r < 4; ++r) {
        float4 v4 = *reinterpret_cast<const float4*>(src + (size_t)r * 128);
        m = fmaxf(m, fmaxf(fmaxf(v4.x, v4.y), fmaxf(v4.z, v4.w)));
    }
    qp[idx] = m / (1.f + __expf(-m));
}

// ---------------- K2: GroupNorm stats per (b,g) ----------------
__global__ void k_gn_stats(const float* __restrict__ x, float* __restrict__ mean,
                           float* __restrict__ rstd) {
    int bg = blockIdx.x;                 // 1024
    int t = threadIdx.x;                 // 256
    const float4* p = reinterpret_cast<const float4*>(x + (size_t)bg * 8192);
    float s = 0.f, ss = 0.f;
#pragma unroll
    for (int r = 0; r < 8; ++r) {
        float4 v4 = p[r * 256 + t];
        s  += v4.x + v4.y + v4.z + v4.w;
        ss += v4.x * v4.x + v4.y * v4.y + v4.z * v4.z + v4.w * v4.w;
    }
    for (int o = 32; o > 0; o >>= 1) { s += __shfl_xor(s, o); ss += __shfl_xor(ss, o); }
    __shared__ float ls[4], lss[4];
    int w = t >> 6;
    if ((t & 63) == 0) { ls[w] = s; lss[w] = ss; }
    __syncthreads();
    if (t == 0) {
        s = ls[0] + ls[1] + ls[2] + ls[3];
        ss = lss[0] + lss[1] + lss[2] + lss[3];
        float mn = s * (1.f / 8192.f);
        float var = ss * (1.f / 8192.f) - mn * mn;
        mean[bg] = mn;
        rstd[bg] = rsqrtf(var + EPSV);
    }
}

// ---------------- K3: GN apply + transpose -> h2nb[B][S][C] (bf16) ----------------
__global__ void k_gn_apply(const float* __restrict__ x, const float* __restrict__ mean,
                           const float* __restrict__ rstd, const float* __restrict__ gw,
                           const float* __restrict__ gb, unsigned short* __restrict__ h2nb) {
    int bid = blockIdx.x;                      // 8192 = 32 * 32 * 8
    int b = bid >> 8, s0 = ((bid >> 3) & 31) << 5, c0 = (bid & 7) << 5;
    int tx = threadIdx.x, ty = threadIdx.y;    // (32,8)
    __shared__ float tile[32][33];
#pragma unroll
    for (int i = 0; i < 4; ++i) {
        int c = c0 + ty + 8 * i;
        float val = x[((size_t)(b * NC + c)) * NS + s0 + tx];
        int bg = b * NG + (c >> 3);
        val = (val - mean[bg]) * rstd[bg] * gw[c] + gb[c];
        tile[ty + 8 * i][tx] = val;            // [c_local][s_local]
    }
    __syncthreads();
#pragma unroll
    for (int i = 0; i < 4; ++i) {
        int s = s0 + ty + 8 * i;
        h2nb[((size_t)(b * NS + s)) * NC + c0 + tx] = f2bf(tile[tx][ty + 8 * i]);
    }
}

// ------------- K4: fold k-half of fp1 through fp2 -> w0,w1,wb,z -------------
__global__ void k_prew(const float* __restrict__ fp1w, const float* __restrict__ fp1b,
                       const float* __restrict__ fp2w, const float* __restrict__ fp2b,
                       float* __restrict__ w0, float* __restrict__ w1,
                       float* __restrict__ wb, float* __restrict__ zs) {
    int c = threadIdx.x;   // 256
    float a0 = 0.f, a1 = 0.f, ab = 0.f;
    for (int kk = 0; kk < 256; ++kk) {
        float f = fp1w[(size_t)kk * 256 + c];
        a0 += f * fp2w[kk * 2];
        a1 += f * fp2w[kk * 2 + 1];
        ab += f * fp2b[kk];
    }
    w0[c] = a0; w1[c] = a1; wb[c] = ab;
    if (c == 0) {
        float z0 = 0.f, z1 = 0.f, zb = 0.f;
        for (int kk = 0; kk < 256; ++kk) {
            float fb = fp1b[kk];
            z0 += fb * fp2w[kk * 2];
            z1 += fb * fp2w[kk * 2 + 1];
            zb += fb * fp2b[kk];
        }
        zs[0] = z0; zs[1] = z1; zs[2] = zb; zs[3] = 0.f;
    }
}

// ------------- K4b: W2 = out_w @ fp1_v (bf16, pre-swizzled), b2 = out_w @ fp1b_v -------------
__global__ __launch_bounds__(256) void k_w2(const float* __restrict__ out_w,
                                            const float* __restrict__ fp1v,
                                            const float* __restrict__ fp1b_v,
                                            unsigned short* __restrict__ w2g,
                                            float* __restrict__ b2) {
    int c = blockIdx.x, t = threadIdx.x;       // c: output channel, t: k (h2n channel)
    __shared__ float ow[256];
    __shared__ float ls[4];
    ow[t] = out_w[(size_t)c * 256 + t];
    __syncthreads();
    float acc = 0.f;
    for (int m = 0; m < 256; ++m) acc = fmaf(ow[m], fp1v[(size_t)m * 256 + t], acc);
    int kc = t >> 5, jl = t & 31;
    w2g[(size_t)(kc * 256 + c) * 32 + (((jl >> 3) ^ ((c >> 1) & 3)) << 3) + (jl & 7)] = f2bf(acc);
    float pb = ow[t] * fp1b_v[t];
    for (int o = 32; o > 0; o >>= 1) pb += __shfl_xor(pb, o);
    if ((t & 63) == 0) ls[t >> 6] = pb;
    __syncthreads();
    if (t == 0) b2[c] = ls[0] + ls[1] + ls[2] + ls[3];
}

// ------------- K5: Vo = h2nb @ W2^T + b2 via MFMA bf16, out in vtg fragment layout -------------
__global__ __launch_bounds__(256) void k_gemm_vo(const unsigned short* __restrict__ h2nb,
                                                 const unsigned short* __restrict__ w2g,
                                                 const float* __restrict__ b2,
                                                 unsigned short* __restrict__ vtg) {
    int m0 = blockIdx.x << 6;                  // 512 blocks
    int t = threadIdx.x;
    int w = t >> 6, lane = t & 63, lo16 = lane & 15, q = lane >> 4;
    __shared__ uint4 at4[2048];                // 32 KB A tile [i:64][granule 0..31 swizzled]
    __shared__ uint4 bt4[1024];                // 16 KB B chunk [c:256][granule 0..3 swizzled]
    unsigned short* atu = (unsigned short*)at4;
    unsigned short* btu = (unsigned short*)bt4;
    const uint4* gh = (const uint4*)h2nb;
    const uint4* gw = (const uint4*)w2g;
    // stage A tile (64 rows x 256 k bf16)
#pragma unroll
    for (int r = 0; r < 8; ++r) {
        int idx = t + (r << 8);
        int i = idx >> 5, qd = idx & 31;
        at4[(i << 5) + (qd ^ (i & 7))] = gh[((size_t)(m0 + i) << 5) + qd];
    }
    f32x4 acc[4][4];
    const f32x4 zero4 = {0.f, 0.f, 0.f, 0.f};
#pragma unroll
    for (int f = 0; f < 4; ++f)
#pragma unroll
        for (int ct = 0; ct < 4; ++ct) acc[f][ct] = zero4;

    for (int kc = 0; kc < 8; ++kc) {
        const uint4* gsrc = gw + (kc << 10);
        uint4 dA = gsrc[t], dB = gsrc[t + 256], dC = gsrc[t + 512], dD = gsrc[t + 768];
        __syncthreads();
        bt4[t] = dA; bt4[t + 256] = dB; bt4[t + 512] = dC; bt4[t + 768] = dD;
        __syncthreads();
        s16x8 af[4];
#pragma unroll
        for (int f = 0; f < 4; ++f) {
            int i = (f << 4) + lo16;
            af[f] = *(const s16x8*)&atu[(i << 8) + ((((kc << 2) + q) ^ (i & 7)) << 3)];
        }
#pragma unroll
        for (int ct = 0; ct < 4; ++ct) {
            int c = (w << 6) + (ct << 4) + lo16;
            s16x8 bf = *(const s16x8*)&btu[(c << 5) + ((q ^ ((c >> 1) & 3)) << 3)];
#pragma unroll
            for (int f = 0; f < 4; ++f)
                acc[f][ct] = __builtin_amdgcn_mfma_f32_16x16x32_bf16(af[f], bf, acc[f][ct], 0, 0, 0);
        }
    }
    float bj[4];
#pragma unroll
    for (int ct = 0; ct < 4; ++ct) bj[ct] = b2[(w << 6) + (ct << 4) + lo16];
#pragma unroll
    for (int f = 0; f < 4; ++f) {
#pragma unroll
        for (int ct = 0; ct < 4; ++ct) {
            int c = (w << 6) + (ct << 4) + lo16;
#pragma unroll
            for (int reg = 0; reg < 4; ++reg) {
                int m = m0 + (f << 4) + (q << 2) + reg;
                int bb = m >> 10, s = m & 1023;
                int kcv = s >> 5, jl = s & 31;
                vtg[(((size_t)(bb * 32 + kcv)) << 13) + c * 32 +
                    (((jl >> 3) ^ ((c >> 1) & 3)) << 3) + (jl & 7)] = f2bf(acc[f][ct][reg] + bj[ct]);
            }
        }
    }
}

// ------------- K6: kp0/kp1/kb per row from h2nb (pre-scaled by SC2) -------------
__global__ void k_kp(const unsigned short* __restrict__ h2nb, const float* __restrict__ w0,
                     const float* __restrict__ w1, const float* __restrict__ wb,
                     const float* __restrict__ zs, float4* __restrict__ kp4) {
    int row = blockIdx.x * 4 + (threadIdx.x >> 6);   // 32768 rows
    int lane = threadIdx.x & 63;
    uint2 hv = *(const uint2*)(h2nb + (size_t)row * 256 + lane * 4);
    float h0 = bf2f(hv.x & 0xffffu), h1 = bf2f(hv.x >> 16);
    float h2 = bf2f(hv.y & 0xffffu), h3 = bf2f(hv.y >> 16);
    float4 v0 = *(const float4*)(w0 + lane * 4);
    float4 v1 = *(const float4*)(w1 + lane * 4);
    float4 vb = *(const float4*)(wb + lane * 4);
    float a0 = h0 * v0.x + h1 * v0.y + h2 * v0.z + h3 * v0.w;
    float a1 = h0 * v1.x + h1 * v1.y + h2 * v1.z + h3 * v1.w;
    float ab = h0 * vb.x + h1 * vb.y + h2 * vb.z + h3 * vb.w;
    for (int o = 32; o > 0; o >>= 1) {
        a0 += __shfl_xor(a0, o); a1 += __shfl_xor(a1, o); ab += __shfl_xor(ab, o);
    }
    if (lane == 0)
        kp4[row] = make_float4((a0 + zs[0]) * SC2, (a1 + zs[1]) * SC2, (ab + zs[2]) * SC2, 0.f);
}

// ------------- K7: per-row softmax max & denominator (kp pre-scaled) -------------
__global__ void k_rowstats(const float4* __restrict__ kp4, const float* __restrict__ qp,
                           float2* __restrict__ mz) {
    int row = blockIdx.x * 4 + (threadIdx.x >> 6);   // 32768
    int lane = threadIdx.x & 63;
    int b = row >> 10, i = row & 1023;
    float qa = qp[(size_t)(b * 2) * NS + i];
    float qb = qp[(size_t)(b * 2 + 1) * NS + i];
    const float4* kp = kp4 + (size_t)b * NS;
    float l[16];
    float m = -1e30f;
#pragma unroll
    for (int tq = 0; tq < 16; ++tq) {
        float4 k4 = kp[lane + 64 * tq];
        float lv = qa * k4.x + qb * k4.y + k4.z;
        l[tq] = lv;
        m = fmaxf(m, lv);
    }
    for (int o = 32; o > 0; o >>= 1) m = fmaxf(m, __shfl_xor(m, o));
    float z = 0.f;
#pragma unroll
    for (int tq = 0; tq < 16; ++tq) z += __expf(l[tq] - m);
    for (int o = 32; o > 0; o >>= 1) z += __shfl_xor(z, o);
    if (lane == 0) mz[row] = make_float2(m, z);
}

// ------------- K8: PV via MFMA bf16 + fused output epilogue -------------
// out[b][c][i] = ((P@Vo)[i][c]/z + out_b[c] + x[b][c][i]) * RS2
__global__ __launch_bounds__(256) void k_pv_mfma(const unsigned short* __restrict__ vtg,
                                                 const float4* __restrict__ kp4,
                                                 const float* __restrict__ qp,
                                                 const float2* __restrict__ mz,
                                                 const float* __restrict__ x,
                                                 const float* __restrict__ out_b,
                                                 float* __restrict__ dout) {
    int bid = blockIdx.x;              // b*16 + it
    int b = bid >> 4, i0 = (bid & 15) << 6;
    int t = threadIdx.x;
    int w = t >> 6, lane = t & 63;
    int lo16 = lane & 15, q = lane >> 4;

    __shared__ uint4 vt4[1024];        // 16 KB: Vo chunk [c:256][64B]; reused as fp32 transpose buf
    __shared__ uint4 pt4[256];         //  4 KB: P tile  [i:64][64B]
    __shared__ float rqa[64], rqb[64], rm[64], rz[64];
    unsigned short* vtu = (unsigned short*)vt4;
    unsigned short* ptu = (unsigned short*)pt4;

    if (t < 64) {
        int row = b * NS + i0 + t;
        rqa[t] = qp[(size_t)(b * 2) * NS + i0 + t];
        rqb[t] = qp[(size_t)(b * 2 + 1) * NS + i0 + t];
        float2 z2 = mz[row];
        rm[t] = z2.x;
        rz[t] = 1.f / z2.y;
    }
    __syncthreads();

    f32x4 acc[4][4];
    const f32x4 zero4 = {0.f, 0.f, 0.f, 0.f};
#pragma unroll
    for (int f = 0; f < 4; ++f)
#pragma unroll
        for (int ct = 0; ct < 4; ++ct) acc[f][ct] = zero4;

    int pj = t & 31, pig = t >> 5;     // producer: column j, row-group of 8
    const float4* kpb = kp4 + ((size_t)b << 10);
    const uint4* gv = (const uint4*)vtg;

    for (int kc = 0; kc < 32; ++kc) {
        const uint4* gsrc = gv + (((size_t)(b * 32 + kc)) << 10);
        uint4 dA = gsrc[t], dB = gsrc[t + 256], dC = gsrc[t + 512], dD = gsrc[t + 768];
        float4 kk = kpb[(kc << 5) + pj];
        unsigned short pe[8];
#pragma unroll
        for (int r = 0; r < 8; ++r) {
            int i = pig * 8 + r;
            float l = fmaf(rqa[i], kk.x, fmaf(rqb[i], kk.y, kk.z)) - rm[i];
            pe[r] = f2bf(__expf(l));
        }
        __syncthreads();               // previous iteration's reads done
        vt4[t] = dA; vt4[t + 256] = dB; vt4[t + 512] = dC; vt4[t + 768] = dD;
#pragma unroll
        for (int r = 0; r < 8; ++r) {
            int i = pig * 8 + r;
            ptu[(i << 5) + (((pj >> 3) ^ ((i >> 1) & 3)) << 3) + (pj & 7)] = pe[r];
        }
        __syncthreads();               // tiles ready
        s16x8 af[4];
#pragma unroll
        for (int f = 0; f < 4; ++f) {
            int i = f * 16 + lo16;
            af[f] = *(const s16x8*)&ptu[(i << 5) + ((q ^ ((i >> 1) & 3)) << 3)];
        }
#pragma unroll
        for (int ct = 0; ct < 4; ++ct) {
            int c = w * 64 + ct * 16 + lo16;
            s16x8 bf = *(const s16x8*)&vtu[(c << 5) + ((q ^ ((c >> 1) & 3)) << 3)];
#pragma unroll
            for (int f = 0; f < 4; ++f)
                acc[f][ct] = __builtin_amdgcn_mfma_f32_16x16x32_bf16(af[f], bf, acc[f][ct], 0, 0, 0);
        }
    }

    // epilogue: transpose 64x256 -> [c][s] via LDS (reuse vt4), fuse bias+residual+RS2
    float* tb = (float*)vt4;           // [256][16], col XOR-swizzled by (c&15)
    float ob = out_b[t];
    __syncthreads();
#pragma unroll
    for (int f = 0; f < 4; ++f) {
#pragma unroll
        for (int ct = 0; ct < 4; ++ct) {
            int c = (w << 6) + (ct << 4) + lo16;
#pragma unroll
            for (int reg = 0; reg < 4; ++reg) {
                int sl = (q << 2) + reg;
                tb[(c << 4) + (sl ^ (c & 15))] = acc[f][ct][reg] * rz[(f << 4) + sl];
            }
        }
        __syncthreads();
        float vals[16];
#pragma unroll
        for (int s = 0; s < 16; ++s) vals[s] = tb[(t << 4) + (s ^ (t & 15))];
        size_t base = (((size_t)(b * 256 + t)) << 10) + i0 + (f << 4);
#pragma unroll
        for (int s4 = 0; s4 < 4; ++s4) {
            float4 xv = *(const float4*)(x + base + (s4 << 2));
            float4 o4;
            o4.x = (vals[s4 * 4 + 0] + ob + xv.x) * RS2;
            o4.y = (vals[s4 * 4 + 1] + ob + xv.y) * RS2;
            o4.z = (vals[s4 * 4 + 2] + ob + xv.z) * RS2;
            o4.w = (vals[s4 * 4 + 3] + ob + xv.w) * RS2;
            *(float4*)(dout + base + (s4 << 2)) = o4;
        }
        __syncthreads();
    }
}

extern "C" void kernel_launch(void* const* d_in, const int* in_sizes, int n_in,
                              void* d_out, int out_size, void* d_ws, size_t ws_size,
                              hipStream_t stream) {
    const float* x     = (const float*)d_in[0];
    const float* cond  = (const float*)d_in[1];
    const float* gn_w  = (const float*)d_in[2];
    const float* gn_b  = (const float*)d_in[3];
    const float* fp1_w = (const float*)d_in[4];
    const float* fp1_b = (const float*)d_in[5];
    const float* fp2_w = (const float*)d_in[6];
    const float* fp2_b = (const float*)d_in[7];
    const float* out_w = (const float*)d_in[8];
    const float* out_b = (const float*)d_in[9];

    float* ws   = (float*)d_ws;
    float* qp   = ws;                        // 65536
    float* mean = ws + 65536;                // 1024
    float* rstd = ws + 66560;                // 1024
    float* w0   = ws + 67584;                // 256
    float* w1   = ws + 67840;                // 256
    float* wb   = ws + 68096;                // 256
    float* zs   = ws + 68352;                // 4 (pad to 256)
    unsigned short* h2nb = (unsigned short*)(ws + 68608);   // 8388608 ushorts (16 MB)
    float* kp4  = ws + 68608 + 4194304;      // 131072  (float4[32768])
    float* mzb  = kp4 + 131072;              // 65536   (float2[32768])
    unsigned short* vtg = (unsigned short*)(mzb + 65536);   // 8388608 ushorts (16 MB)
    unsigned short* w2g = (unsigned short*)(mzb + 65536 + 4194304);  // 65536 ushorts
    float* b2   = mzb + 65536 + 4194304 + 32768;            // 256

    k_pool_silu<<<256, 256, 0, stream>>>(cond, qp);
    k_gn_stats<<<1024, 256, 0, stream>>>(x, mean, rstd);
    k_gn_apply<<<8192, dim3(32, 8), 0, stream>>>(x, mean, rstd, gn_w, gn_b, h2nb);
    k_prew<<<1, 256, 0, stream>>>(fp1_w, fp1_b, fp2_w, fp2_b, w0, w1, wb, zs);
    k_w2<<<256, 256, 0, stream>>>(out_w, fp1_w + 256 * 256, fp1_b + 256, w2g, b2);
    k_gemm_vo<<<512, 256, 0, stream>>>(h2nb, w2g, b2, vtg);
    k_kp<<<8192, 256, 0, stream>>>(h2nb, w0, w1, wb, zs, (float4*)kp4);
    k_rowstats<<<8192, 256, 0, stream>>>((const float4*)kp4, qp, (float2*)mzb);
    k_pv_mfma<<<512, 256, 0, stream>>>(vtg, (const float4*)kp4, qp, (const float2*)mzb,
                                       x, out_b, (float*)d_out);
}

// Round 4
// 120.318 us; speedup vs baseline: 4.3777x; 1.2038x over previous
//
#include <hip/hip_runtime.h>
#include <math.h>

// Problem constants (fixed by setup_inputs)
#define NB 32      // batch
#define NC 256     // channels
#define NS 1024    // spatial (32*32)
#define NG 32      // groups
#define EPSV 1e-5f
#define RS2 0.70710678118654752f  // 1/sqrt(2)
#define SC2 0.0625f               // C^-0.5 = 1/16

typedef __attribute__((ext_vector_type(8))) short s16x8;
typedef __attribute__((ext_vector_type(4))) float f32x4;

#define WAITVM4 asm volatile("s_waitcnt vmcnt(4)" ::: "memory")
#define WAITVM0 asm volatile("s_waitcnt vmcnt(0)" ::: "memory")
#define WAITLGKM asm volatile("s_waitcnt lgkmcnt(0)" ::: "memory")
#define SCHEDB __builtin_amdgcn_sched_barrier(0)
#define SBAR __builtin_amdgcn_s_barrier()

__device__ __forceinline__ unsigned short f2bf(float f) {
    unsigned u = __float_as_uint(f);
    return (unsigned short)((u + 0x7fffu + ((u >> 16) & 1u)) >> 16);
}
__device__ __forceinline__ float bf2f(unsigned u16) {
    return __uint_as_float(u16 << 16);
}

typedef __attribute__((address_space(1))) const unsigned int gas_u32;
typedef __attribute__((address_space(3))) unsigned int las_u32;
__device__ __forceinline__ void gll16(const void* g, void* l) {
    // async global->LDS, 16B/lane; LDS dest = wave-uniform base + lane*16
    __builtin_amdgcn_global_load_lds((gas_u32*)g, (las_u32*)l, 16, 0, 0);
}

// ---------------- K1: 4x4 maxpool + SiLU -> qp[B][2][S] ----------------
__global__ void k_pool_silu(const float* __restrict__ cond, float* __restrict__ qp) {
    int idx = blockIdx.x * 256 + threadIdx.x;        // 65536 outputs
    int ow = idx & 31, oh = (idx >> 5) & 31;
    int bd = idx >> 10;                              // b*2+d
    const float* src = cond + (((size_t)bd * 128 + oh * 4) * 128 + ow * 4);
    float m = -1e30f;
#pragma unroll
    for (int r = 0; r < 4; ++r) {
        float4 v4 = *reinterpret_cast<const float4*>(src + (size_t)r * 128);
        m = fmaxf(m, fmaxf(fmaxf(v4.x, v4.y), fmaxf(v4.z, v4.w)));
    }
    qp[idx] = m / (1.f + __expf(-m));
}

// ---------------- K2: GroupNorm stats per (b,g) ----------------
__global__ void k_gn_stats(const float* __restrict__ x, float* __restrict__ mean,
                           float* __restrict__ rstd) {
    int bg = blockIdx.x;                 // 1024
    int t = threadIdx.x;                 // 256
    const float4* p = reinterpret_cast<const float4*>(x + (size_t)bg * 8192);
    float s = 0.f, ss = 0.f;
#pragma unroll
    for (int r = 0; r < 8; ++r) {
        float4 v4 = p[r * 256 + t];
        s  += v4.x + v4.y + v4.z + v4.w;
        ss += v4.x * v4.x + v4.y * v4.y + v4.z * v4.z + v4.w * v4.w;
    }
    for (int o = 32; o > 0; o >>= 1) { s += __shfl_xor(s, o); ss += __shfl_xor(ss, o); }
    __shared__ float ls[4], lss[4];
    int w = t >> 6;
    if ((t & 63) == 0) { ls[w] = s; lss[w] = ss; }
    __syncthreads();
    if (t == 0) {
        s = ls[0] + ls[1] + ls[2] + ls[3];
        ss = lss[0] + lss[1] + lss[2] + lss[3];
        float mn = s * (1.f / 8192.f);
        float var = ss * (1.f / 8192.f) - mn * mn;
        mean[bg] = mn;
        rstd[bg] = rsqrtf(var + EPSV);
    }
}

// ---------------- K3: GN apply + transpose -> h2nb[B][S][C] (bf16) ----------------
__global__ void k_gn_apply(const float* __restrict__ x, const float* __restrict__ mean,
                           const float* __restrict__ rstd, const float* __restrict__ gw,
                           const float* __restrict__ gb, unsigned short* __restrict__ h2nb) {
    int bid = blockIdx.x;                      // 8192 = 32 * 32 * 8
    int b = bid >> 8, s0 = ((bid >> 3) & 31) << 5, c0 = (bid & 7) << 5;
    int tx = threadIdx.x, ty = threadIdx.y;    // (32,8)
    __shared__ float tile[32][33];
#pragma unroll
    for (int i = 0; i < 4; ++i) {
        int c = c0 + ty + 8 * i;
        float val = x[((size_t)(b * NC + c)) * NS + s0 + tx];
        int bg = b * NG + (c >> 3);
        val = (val - mean[bg]) * rstd[bg] * gw[c] + gb[c];
        tile[ty + 8 * i][tx] = val;            // [c_local][s_local]
    }
    __syncthreads();
#pragma unroll
    for (int i = 0; i < 4; ++i) {
        int s = s0 + ty + 8 * i;
        h2nb[((size_t)(b * NS + s)) * NC + c0 + tx] = f2bf(tile[tx][ty + 8 * i]);
    }
}

// ------------- K4: fold k-half of fp1 through fp2 -> w0,w1,wb,z -------------
__global__ void k_prew(const float* __restrict__ fp1w, const float* __restrict__ fp1b,
                       const float* __restrict__ fp2w, const float* __restrict__ fp2b,
                       float* __restrict__ w0, float* __restrict__ w1,
                       float* __restrict__ wb, float* __restrict__ zs) {
    int c = threadIdx.x;   // 256
    float a0 = 0.f, a1 = 0.f, ab = 0.f;
    for (int kk = 0; kk < 256; ++kk) {
        float f = fp1w[(size_t)kk * 256 + c];
        a0 += f * fp2w[kk * 2];
        a1 += f * fp2w[kk * 2 + 1];
        ab += f * fp2b[kk];
    }
    w0[c] = a0; w1[c] = a1; wb[c] = ab;
    if (c == 0) {
        float z0 = 0.f, z1 = 0.f, zb = 0.f;
        for (int kk = 0; kk < 256; ++kk) {
            float fb = fp1b[kk];
            z0 += fb * fp2w[kk * 2];
            z1 += fb * fp2w[kk * 2 + 1];
            zb += fb * fp2b[kk];
        }
        zs[0] = z0; zs[1] = z1; zs[2] = zb; zs[3] = 0.f;
    }
}

// ------------- K4b: W2 = out_w @ fp1_v (bf16, pre-swizzled), b2 = out_w @ fp1b_v -------------
__global__ __launch_bounds__(256) void k_w2(const float* __restrict__ out_w,
                                            const float* __restrict__ fp1v,
                                            const float* __restrict__ fp1b_v,
                                            unsigned short* __restrict__ w2g,
                                            float* __restrict__ b2) {
    int c = blockIdx.x, t = threadIdx.x;       // c: output channel, t: k (h2n channel)
    __shared__ float ow[256];
    __shared__ float ls[4];
    ow[t] = out_w[(size_t)c * 256 + t];
    __syncthreads();
    float acc = 0.f;
    for (int m = 0; m < 256; ++m) acc = fmaf(ow[m], fp1v[(size_t)m * 256 + t], acc);
    int kc = t >> 5, jl = t & 31;
    w2g[(size_t)(kc * 256 + c) * 32 + (((jl >> 3) ^ ((c >> 1) & 3)) << 3) + (jl & 7)] = f2bf(acc);
    float pb = ow[t] * fp1b_v[t];
    for (int o = 32; o > 0; o >>= 1) pb += __shfl_xor(pb, o);
    if ((t & 63) == 0) ls[t >> 6] = pb;
    __syncthreads();
    if (t == 0) b2[c] = ls[0] + ls[1] + ls[2] + ls[3];
}

// ------------- K5: Vo = h2nb @ W2^T + b2 (MFMA bf16, async B staging) + kp epilogue -------------
__global__ __launch_bounds__(256) void k_gvo(const unsigned short* __restrict__ h2nb,
                                             const unsigned short* __restrict__ w2g,
                                             const float* __restrict__ b2,
                                             const float* __restrict__ w0,
                                             const float* __restrict__ w1,
                                             const float* __restrict__ wb,
                                             const float* __restrict__ zsp,
                                             unsigned short* __restrict__ vtg,
                                             float4* __restrict__ kp4) {
    int m0 = blockIdx.x << 6;                  // 512 blocks
    int t = threadIdx.x;
    int w = t >> 6, lane = t & 63, lo16 = lane & 15, q = lane >> 4;
    __shared__ uint4 at4[2048];                // 32 KB A tile [i:64][32 granules swizzled]
    __shared__ uint4 bt4[2][1024];             // 2 x 16 KB B chunk (double buffered)
    __shared__ float4 kpp[4][64];              // kp partials
    unsigned short* atu = (unsigned short*)at4;

    const uint4* gh = (const uint4*)h2nb;
    uint4 areg[8];
#pragma unroll
    for (int r = 0; r < 8; ++r) {
        int idx = t + (r << 8);
        areg[r] = gh[((size_t)(m0 + (idx >> 5)) << 5) + (idx & 31)];
    }
    const uint4* gw = (const uint4*)w2g;
    {   // async-stage chunk 0 (each wave stages the quarter it will read)
        uint4* ldst = &bt4[0][(w << 8)];
        gll16(gw + (w << 8) + lane, ldst);
        gll16(gw + (w << 8) + 64 + lane, ldst + 64);
        gll16(gw + (w << 8) + 128 + lane, ldst + 128);
        gll16(gw + (w << 8) + 192 + lane, ldst + 192);
    }
    WAITVM4;    // A-tile regs ready; chunk-0 DMA still in flight
    SCHEDB;
#pragma unroll
    for (int r = 0; r < 8; ++r) {
        int idx = t + (r << 8);
        int i = idx >> 5, qd = idx & 31;
        at4[(i << 5) + (qd ^ (i & 7))] = areg[r];
    }
    WAITLGKM;
    SCHEDB;
    SBAR;

    f32x4 acc[4][4];
    const f32x4 zero4 = {0.f, 0.f, 0.f, 0.f};
#pragma unroll
    for (int f = 0; f < 4; ++f)
#pragma unroll
        for (int ct = 0; ct < 4; ++ct) acc[f][ct] = zero4;

    for (int kc = 0; kc < 8; ++kc) {
        if (kc < 7) {
            const uint4* gsrc = gw + ((kc + 1) << 10);
            uint4* ldst = &bt4[(kc + 1) & 1][(w << 8)];
            gll16(gsrc + (w << 8) + lane, ldst);
            gll16(gsrc + (w << 8) + 64 + lane, ldst + 64);
            gll16(gsrc + (w << 8) + 128 + lane, ldst + 128);
            gll16(gsrc + (w << 8) + 192 + lane, ldst + 192);
            WAITVM4;
        } else {
            WAITVM0;
        }
        SCHEDB;
        const unsigned short* btu = (const unsigned short*)bt4[kc & 1];
        s16x8 af[4];
#pragma unroll
        for (int f = 0; f < 4; ++f) {
            int i = (f << 4) + lo16;
            af[f] = *(const s16x8*)&atu[(i << 8) + ((((kc << 2) + q) ^ (i & 7)) << 3)];
        }
#pragma unroll
        for (int ct = 0; ct < 4; ++ct) {
            int c = (w << 6) + (ct << 4) + lo16;
            s16x8 bf = *(const s16x8*)&btu[(c << 5) + ((q ^ ((c >> 1) & 3)) << 3)];
#pragma unroll
            for (int f = 0; f < 4; ++f)
                acc[f][ct] = __builtin_amdgcn_mfma_f32_16x16x32_bf16(af[f], bf, acc[f][ct], 0, 0, 0);
        }
    }

    // vtg epilogue (pre-swizzled fragment layout for PV's async staging)
    float bj[4];
#pragma unroll
    for (int ct = 0; ct < 4; ++ct) bj[ct] = b2[(w << 6) + (ct << 4) + lo16];
#pragma unroll
    for (int f = 0; f < 4; ++f) {
#pragma unroll
        for (int ct = 0; ct < 4; ++ct) {
            int c = (w << 6) + (ct << 4) + lo16;
#pragma unroll
            for (int reg = 0; reg < 4; ++reg) {
                int m = m0 + (f << 4) + (q << 2) + reg;
                int bb = m >> 10, s = m & 1023;
                int kcv = s >> 5, jl = s & 31;
                vtg[(((size_t)(bb * 32 + kcv)) << 13) + c * 32 +
                    (((jl >> 3) ^ ((c >> 1) & 3)) << 3) + (jl & 7)] = f2bf(acc[f][ct][reg] + bj[ct]);
            }
        }
    }

    // kp epilogue: kp4[m0+i] from the A-tile in LDS (row i, wave covers k-quarter)
    {
        int i = t & 63, quarter = t >> 6;      // k-range quarter*64..+64, wave-uniform
        float a0 = 0.f, a1 = 0.f, ab = 0.f;
#pragma unroll
        for (int gg = 0; gg < 8; ++gg) {
            int g = (quarter << 3) + gg;
            s16x8 hv = *(const s16x8*)&atu[(i << 8) + ((g ^ (i & 7)) << 3)];
#pragma unroll
            for (int e = 0; e < 8; ++e) {
                float h = bf2f((unsigned short)hv[e]);
                int k = (g << 3) + e;
                a0 = fmaf(h, w0[k], a0);
                a1 = fmaf(h, w1[k], a1);
                ab = fmaf(h, wb[k], ab);
            }
        }
        kpp[quarter][i] = make_float4(a0, a1, ab, 0.f);
        WAITLGKM;
        SCHEDB;
        SBAR;
        if (t < 64) {
            float4 p0 = kpp[0][t], p1 = kpp[1][t], p2 = kpp[2][t], p3 = kpp[3][t];
            kp4[m0 + t] = make_float4((p0.x + p1.x + p2.x + p3.x + zsp[0]) * SC2,
                                      (p0.y + p1.y + p2.y + p3.y + zsp[1]) * SC2,
                                      (p0.z + p1.z + p2.z + p3.z + zsp[2]) * SC2, 0.f);
        }
    }
}

// ------------- K6: PV flash (online softmax, async V staging, fused epilogue) -------------
// out[b][c][i] = ((P@Vo)[i][c]/z + out_b[c] + x[b][c][i]) * RS2
__global__ __launch_bounds__(256) void k_pv_flash(const unsigned short* __restrict__ vtg,
                                                  const float4* __restrict__ kp4,
                                                  const float* __restrict__ qp,
                                                  const float* __restrict__ x,
                                                  const float* __restrict__ out_b,
                                                  float* __restrict__ dout) {
    int raw = blockIdx.x;
    int bid = ((raw & 7) << 6) | (raw >> 3);   // XCD swizzle: 16 blocks/batch share an XCD's L2
    int b = bid >> 4, i0 = (bid & 15) << 6;
    int t = threadIdx.x;
    int w = t >> 6, lane = t & 63;
    int lo16 = lane & 15, q = lane >> 4;
    int pj = t & 31, pig = t >> 5;             // producer: column pj, rows pig*8..+8

    __shared__ uint4 vbuf[2][1024];            // 2 x 16 KB Vo chunk (double buffered)
    __shared__ uint4 ptb[2][256];              // 2 x 4 KB P tile (double buffered)
    __shared__ float4 kps[1024];               // 16 KB: kp4[b]
    __shared__ float facs[2][8];               // rescale factors per 8-row group
    __shared__ float rzs[64];

    const float4* kp4b = kp4 + ((size_t)b << 10);
    // prologue loads (order matters for vmcnt counting: [kps x4, q x4, gll x4])
    float4 kv0 = kp4b[t], kv1 = kp4b[256 + t], kv2 = kp4b[512 + t], kv3 = kp4b[768 + t];
    const float* qpa = qp + ((size_t)(b * 2)) * NS + i0 + pig * 8;
    float4 qa0 = *(const float4*)qpa, qa1 = *(const float4*)(qpa + 4);
    float4 qb0 = *(const float4*)(qpa + NS), qb1 = *(const float4*)(qpa + NS + 4);
    const uint4* gv = (const uint4*)vtg + ((size_t)b << 15);
    {
        uint4* ldst = &vbuf[0][(w << 8)];
        gll16(gv + (w << 8) + lane, ldst);
        gll16(gv + (w << 8) + 64 + lane, ldst + 64);
        gll16(gv + (w << 8) + 128 + lane, ldst + 128);
        gll16(gv + (w << 8) + 192 + lane, ldst + 192);
    }
    WAITVM4;    // kps+q data ready; chunk-0 DMA in flight
    SCHEDB;
    kps[t] = kv0; kps[256 + t] = kv1; kps[512 + t] = kv2; kps[768 + t] = kv3;
    WAITLGKM;
    SCHEDB;
    SBAR;

    float qa_r[8] = {qa0.x, qa0.y, qa0.z, qa0.w, qa1.x, qa1.y, qa1.z, qa1.w};
    float qb_r[8] = {qb0.x, qb0.y, qb0.z, qb0.w, qb1.x, qb1.y, qb1.z, qb1.w};
    float m = -1e30f;
    float z_r[8] = {0.f, 0.f, 0.f, 0.f, 0.f, 0.f, 0.f, 0.f};

    f32x4 acc[4][4];
    const f32x4 zero4 = {0.f, 0.f, 0.f, 0.f};
#pragma unroll
    for (int f = 0; f < 4; ++f)
#pragma unroll
        for (int ct = 0; ct < 4; ++ct) acc[f][ct] = zero4;

    for (int kc = 0; kc < 32; ++kc) {
        WAITLGKM;   // prior ds_reads of the slot about to be DMA'd are retired
        if (kc < 31) {
            const uint4* gsrc = gv + ((kc + 1) << 10);
            uint4* ldst = &vbuf[(kc + 1) & 1][(w << 8)];
            gll16(gsrc + (w << 8) + lane, ldst);
            gll16(gsrc + (w << 8) + 64 + lane, ldst + 64);
            gll16(gsrc + (w << 8) + 128 + lane, ldst + 128);
            gll16(gsrc + (w << 8) + 192 + lane, ldst + 192);
        }
        // ---- producer: logits -> online max/z -> P tile ----
        float4 kk = kps[(kc << 5) + pj];
        float l[8];
        float pmax = -1e30f;
#pragma unroll
        for (int r = 0; r < 8; ++r) {
            l[r] = fmaf(qa_r[r], kk.x, fmaf(qb_r[r], kk.y, kk.z));
            pmax = fmaxf(pmax, l[r]);
        }
#pragma unroll
        for (int o = 16; o > 0; o >>= 1) pmax = fmaxf(pmax, __shfl_xor(pmax, o));
        float fac = 1.f;
        if (pmax > m + 8.f) {                  // defer-max: rescale only on real growth
            fac = __expf(m - pmax);
            m = pmax;
#pragma unroll
            for (int r = 0; r < 8; ++r) z_r[r] *= fac;
        }
        unsigned short* ptu = (unsigned short*)ptb[kc & 1];
#pragma unroll
        for (int r = 0; r < 8; ++r) {
            float e = __expf(l[r] - m);
            z_r[r] += e;
            int i = pig * 8 + r;
            ptu[(i << 5) + (((pj >> 3) ^ ((i >> 1) & 3)) << 3) + (pj & 7)] = f2bf(e);
        }
        if (pj == 0) facs[kc & 1][pig] = fac;
        WAITLGKM;
        SCHEDB;
        SBAR;                                   // P tile + facs visible
        // ---- consumer ----
        float ffv[4];
        {
            const float* fp = &facs[kc & 1][0];
#pragma unroll
            for (int f = 0; f < 4; ++f) ffv[f] = fp[f * 2 + (q >> 1)];
        }
        if (ffv[0] != 1.f || ffv[1] != 1.f || ffv[2] != 1.f || ffv[3] != 1.f) {
#pragma unroll
            for (int f = 0; f < 4; ++f)
#pragma unroll
                for (int ct = 0; ct < 4; ++ct) acc[f][ct] *= ffv[f];
        }
        if (kc < 31) { WAITVM4; } else { WAITVM0; }   // own wave's V quarter ready
        SCHEDB;
        const unsigned short* ptc = (const unsigned short*)ptb[kc & 1];
        const unsigned short* vtu = (const unsigned short*)vbuf[kc & 1];
        s16x8 af[4];
#pragma unroll
        for (int f = 0; f < 4; ++f) {
            int i = (f << 4) + lo16;
            af[f] = *(const s16x8*)&ptc[(i << 5) + ((q ^ ((i >> 1) & 3)) << 3)];
        }
#pragma unroll
        for (int ct = 0; ct < 4; ++ct) {
            int c = (w << 6) + (ct << 4) + lo16;
            s16x8 bf = *(const s16x8*)&vtu[(c << 5) + ((q ^ ((c >> 1) & 3)) << 3)];
#pragma unroll
            for (int f = 0; f < 4; ++f)
                acc[f][ct] = __builtin_amdgcn_mfma_f32_16x16x32_bf16(af[f], bf, acc[f][ct], 0, 0, 0);
        }
    }

    // finalize z across the 32 producer columns
#pragma unroll
    for (int r = 0; r < 8; ++r) {
#pragma unroll
        for (int o = 16; o > 0; o >>= 1) z_r[r] += __shfl_xor(z_r[r], o);
    }
    if (pj == 0) {
#pragma unroll
        for (int r = 0; r < 8; ++r) rzs[pig * 8 + r] = 1.f / z_r[r];
    }
    WAITLGKM;
    SCHEDB;
    SBAR;

    // epilogue: transpose 64x256 -> [c][s] via LDS (reuse vbuf), fuse bias+residual+RS2
    float* tb = (float*)&vbuf[0][0];           // [256][16], col XOR-swizzled by (c&15)
    float ob = out_b[t];
#pragma unroll
    for (int f = 0; f < 4; ++f) {
#pragma unroll
        for (int ct = 0; ct < 4; ++ct) {
            int c = (w << 6) + (ct << 4) + lo16;
#pragma unroll
            for (int reg = 0; reg < 4; ++reg) {
                int sl = (q << 2) + reg;
                tb[(c << 4) + (sl ^ (c & 15))] = acc[f][ct][reg] * rzs[(f << 4) + sl];
            }
        }
        __syncthreads();
        float vals[16];
#pragma unroll
        for (int s = 0; s < 16; ++s) vals[s] = tb[(t << 4) + (s ^ (t & 15))];
        size_t base = (((size_t)(b * 256 + t)) << 10) + i0 + (f << 4);
#pragma unroll
        for (int s4 = 0; s4 < 4; ++s4) {
            float4 xv = *(const float4*)(x + base + (s4 << 2));
            float4 o4;
            o4.x = (vals[s4 * 4 + 0] + ob + xv.x) * RS2;
            o4.y = (vals[s4 * 4 + 1] + ob + xv.y) * RS2;
            o4.z = (vals[s4 * 4 + 2] + ob + xv.z) * RS2;
            o4.w = (vals[s4 * 4 + 3] + ob + xv.w) * RS2;
            *(float4*)(dout + base + (s4 << 2)) = o4;
        }
        __syncthreads();
    }
}

extern "C" void kernel_launch(void* const* d_in, const int* in_sizes, int n_in,
                              void* d_out, int out_size, void* d_ws, size_t ws_size,
                              hipStream_t stream) {
    const float* x     = (const float*)d_in[0];
    const float* cond  = (const float*)d_in[1];
    const float* gn_w  = (const float*)d_in[2];
    const float* gn_b  = (const float*)d_in[3];
    const float* fp1_w = (const float*)d_in[4];
    const float* fp1_b = (const float*)d_in[5];
    const float* fp2_w = (const float*)d_in[6];
    const float* fp2_b = (const float*)d_in[7];
    const float* out_w = (const float*)d_in[8];
    const float* out_b = (const float*)d_in[9];

    float* ws   = (float*)d_ws;
    float* qp   = ws;                        // 65536
    float* mean = ws + 65536;                // 1024
    float* rstd = ws + 66560;                // 1024
    float* w0   = ws + 67584;                // 256
    float* w1   = ws + 67840;                // 256
    float* wb   = ws + 68096;                // 256
    float* zs   = ws + 68352;                // 4 (pad to 256)
    unsigned short* h2nb = (unsigned short*)(ws + 68608);       // 8M ushorts (16 MB)
    float* kp4  = ws + 68608 + 4194304;      // 131072 floats (float4[32768])
    unsigned short* vtg = (unsigned short*)(kp4 + 131072);      // 8M ushorts (16 MB)
    unsigned short* w2g = (unsigned short*)(kp4 + 131072 + 4194304);  // 65536 ushorts
    float* b2   = kp4 + 131072 + 4194304 + 32768;               // 256

    k_pool_silu<<<256, 256, 0, stream>>>(cond, qp);
    k_gn_stats<<<1024, 256, 0, stream>>>(x, mean, rstd);
    k_gn_apply<<<8192, dim3(32, 8), 0, stream>>>(x, mean, rstd, gn_w, gn_b, h2nb);
    k_prew<<<1, 256, 0, stream>>>(fp1_w, fp1_b, fp2_w, fp2_b, w0, w1, wb, zs);
    k_w2<<<256, 256, 0, stream>>>(out_w, fp1_w + 256 * 256, fp1_b + 256, w2g, b2);
    k_gvo<<<512, 256, 0, stream>>>(h2nb, w2g, b2, w0, w1, wb, zs, vtg, (float4*)kp4);
    k_pv_flash<<<512, 256, 0, stream>>>(vtg, (const float4*)kp4, qp, x, out_b, (float*)d_out);
}